// Round 8
// baseline (130.721 us; speedup 1.0000x reference)
//
#include <hip/hip_runtime.h>
#include <stdint.h>

typedef unsigned short u16;
typedef __attribute__((ext_vector_type(8))) short short8;
typedef __attribute__((ext_vector_type(4))) float f32x4;
typedef __attribute__((ext_vector_type(2))) uint32_t u32x2;

#define B_      16
#define L_      1024
#define H_      1024
#define G_      128
#define M_TOT   16368            // B*(L-1)
#define K_TOT   3072
#define OUT_SEG 2095104          // M_TOT*G_
#define KL_IDX  (4*OUT_SEG)
#define KL_BLOCKS 4092           // M_TOT / 4 exactly
#define NKT     96               // K_TOT / 32

// ws layout
#define WS_WT_OFF    0           // bf16 W'T [512][3072] = 3,145,728 B
#define WS_BIAS_OFF  3145728     // float[512]
#define WS_PART_OFF  3147776     // float[4092] block partials

__device__ inline u16 f2bf(float f) {
    union { float f; uint32_t u; } x; x.f = f;
    uint32_t u = x.u;
    return (u16)((u + 0x7fffu + ((u >> 16) & 1u)) >> 16);
}

__device__ inline void gload16(const void* g, void* l) {
    __builtin_amdgcn_global_load_lds(
        (const __attribute__((address_space(1))) void*)g,
        (__attribute__((address_space(3))) void*)l, 16, 0, 0);
}

// ---------------- prep: build W'T (bf16, [512][3072]) + bias[512] ------------
__global__ __launch_bounds__(256) void prep_kernel(
    const float* __restrict__ Wzm, const float* __restrict__ bzm,
    const float* __restrict__ Wzv, const float* __restrict__ bzv,
    const float* __restrict__ Wqm, const float* __restrict__ bqm,
    const float* __restrict__ Wqv, const float* __restrict__ bqv,
    u16* __restrict__ wt, float* __restrict__ bias)
{
    int n = blockIdx.x;                 // 0..511 (output column)
    int tid = threadIdx.x;
    const float* W; const float* bsrc; int g; int kmax;
    if (n < 128)      { W = Wzm; bsrc = bzm; g = n;       kmax = 2048; }
    else if (n < 256) { W = Wzv; bsrc = bzv; g = n - 128; kmax = 2048; }
    else if (n < 384) { W = Wqm; bsrc = bqm; g = n - 256; kmax = 3072; }
    else              { W = Wqv; bsrc = bqv; g = n - 384; kmax = 3072; }
    if (tid == 0) bias[n] = bsrc[g];
    #pragma unroll
    for (int i = 0; i < 12; ++i) {
        int k = i * 256 + tid;
        float v = (k < kmax) ? W[(size_t)k * G_ + g] : 0.0f;
        wt[(size_t)n * K_TOT + k] = f2bf(v);
    }
}

// ---------------- GEMM: out[m, 0:512] = ce @ W' + bias ----------------------
// BM=64, BN=64, BK=32, ONE wave per block (64 threads) -> NO barriers.
// 2048 blocks = 8 independent waves/CU, each with its own counted-vmcnt
// pipeline: A 2-phase-deep in regs (X/Y named sets), B 1-deep via gload_lds.
// Per phase: issue A(kt+2), issue B(kt+1), s_waitcnt vmcnt(12), compute(kt),
// cvt+swizzled-ds_write A(kt+1). vmcnt never drains to 0 in the main loop.
// LDS swizzle (rows = 64B = 4 slots of 16B): slot ^= (r&3)^((r>>2)&3).
__global__ __launch_bounds__(64, 2) void gemm_kernel(
    const float* __restrict__ events, const float* __restrict__ contexts,
    const u16* __restrict__ wt, const float* __restrict__ bias,
    float* __restrict__ out)
{
    __shared__ u16 Ab[2][64 * 32];    // bf16 A tile, swizzled (4 KB each)
    __shared__ u16 Bb[2][64 * 32];    // bf16 B tile, swizzled (4 KB each)

    const int l   = threadIdx.x;      // 0..63
    const int bid = blockIdx.x;
    // XCD swizzle: 8 nb-blocks sharing an A panel land on one XCD.
    const int xcd = bid & 7;
    const int nb  = (bid >> 3) & 7;          // 0..7 (64-col output block)
    const int mp  = xcd * 32 + (bid >> 6);   // 0..255
    const int m0  = mp * 64;

    const int lr  = l & 15;
    const int kg  = l >> 4;                  // 16B k-slot group 0..3
    const int fsw = (lr & 3) ^ ((lr >> 2) & 3);
    const int afr = lr * 32 + ((kg ^ fsw) << 3);   // u16 idx; frag i at +i*512

    // ---- A-load setup: lane covers rows {(l>>3)+8j}, 4 floats at col (l&7)*4
    //      -> per instr 8 lanes read 128B contiguous (coalesced).
    uint32_t evoff[8], ctoff[8];
    int woff[8];
    #pragma unroll
    for (int j = 0; j < 8; ++j) {
        int rr = (l >> 3) + 8 * j;
        int m = m0 + rr; if (m > M_TOT - 1) m = M_TOT - 1;
        int b = m / 1023;
        int t = m - b * 1023;
        evoff[j] = (uint32_t)(b * L_ + t) * H_ + (l & 7) * 4;
        ctoff[j] = (uint32_t)(b * (L_ - 1) + t) * H_ + (l & 7) * 4;
        int fw = (rr & 3) ^ ((rr >> 2) & 3);
        int slot = ((l & 7) >> 1) ^ fw;
        woff[j] = rr * 32 + slot * 8 + (l & 1) * 4;   // u16 units, 8B-aligned
    }

    // ---- B staging: 4 gload_lds chunks, source-preswizzled, 64B segments ----
    const int bfw = ((l >> 2) & 3) ^ ((l >> 4) & 3);
    const u16* bsrc = wt + (size_t)(nb * 64 + (l >> 2)) * K_TOT
                         + (size_t)(((l & 3) ^ bfw) * 8);

    f32x4 acc[4][4];
    #pragma unroll
    for (int i = 0; i < 4; ++i)
        #pragma unroll
        for (int j = 0; j < 4; ++j)
            acc[i][j] = (f32x4){0.f, 0.f, 0.f, 0.f};

    auto stageB = [&](int buf, int kt) {
        int k0 = kt * 32;
        #pragma unroll
        for (int it = 0; it < 4; ++it)
            gload16(bsrc + (size_t)it * 16 * K_TOT + k0,
                    &Bb[buf][(it * 64 + l) * 8]);
    };
    auto compute = [&](int buf) {
        short8 a[4], bf[4];
        #pragma unroll
        for (int i = 0; i < 4; ++i)
            a[i] = *(const short8*)&Ab[buf][afr + i * 512];
        #pragma unroll
        for (int j = 0; j < 4; ++j)
            bf[j] = *(const short8*)&Bb[buf][afr + j * 512];
        #pragma unroll
        for (int i = 0; i < 4; ++i)
            #pragma unroll
            for (int j = 0; j < 4; ++j)
                acc[i][j] = __builtin_amdgcn_mfma_f32_16x16x32_bf16(
                    a[i], bf[j], acc[i][j], 0, 0, 0);
    };

    // Named A prefetch sets (2-phase-deep)
    f32x4 X0, X1, X2, X3, X4, X5, X6, X7;
    f32x4 Y0, Y1, Y2, Y3, Y4, Y5, Y6, Y7;

#define LOADA(p, KT)                                                           \
    {                                                                          \
        int k0_ = (KT) * 32;                                                   \
        int rg_ = k0_ >> 10;                                                   \
        int kq_ = k0_ & 1023;                                                  \
        const float* s0_ = ((rg_ == 2) ? contexts : events) + kq_              \
                           + ((rg_ == 1) ? H_ : 0);                            \
        p##0 = *(const f32x4*)(s0_ + (rg_ == 2 ? ctoff[0] : evoff[0]));        \
        p##1 = *(const f32x4*)(s0_ + (rg_ == 2 ? ctoff[1] : evoff[1]));        \
        p##2 = *(const f32x4*)(s0_ + (rg_ == 2 ? ctoff[2] : evoff[2]));        \
        p##3 = *(const f32x4*)(s0_ + (rg_ == 2 ? ctoff[3] : evoff[3]));        \
        p##4 = *(const f32x4*)(s0_ + (rg_ == 2 ? ctoff[4] : evoff[4]));        \
        p##5 = *(const f32x4*)(s0_ + (rg_ == 2 ? ctoff[5] : evoff[5]));        \
        p##6 = *(const f32x4*)(s0_ + (rg_ == 2 ? ctoff[6] : evoff[6]));        \
        p##7 = *(const f32x4*)(s0_ + (rg_ == 2 ? ctoff[7] : evoff[7]));        \
    }

#define CVT1(p, J, BUF)                                                        \
    {                                                                          \
        uint32_t lo_, hi_;                                                     \
        asm("v_cvt_pk_bf16_f32 %0, %1, %2" : "=v"(lo_) : "v"(p##J[0]), "v"(p##J[1])); \
        asm("v_cvt_pk_bf16_f32 %0, %1, %2" : "=v"(hi_) : "v"(p##J[2]), "v"(p##J[3])); \
        *(u32x2*)&Ab[BUF][woff[J]] = (u32x2){lo_, hi_};                        \
    }
#define CVTW(p, BUF)                                                           \
    CVT1(p, 0, BUF) CVT1(p, 1, BUF) CVT1(p, 2, BUF) CVT1(p, 3, BUF)            \
    CVT1(p, 4, BUF) CVT1(p, 5, BUF) CVT1(p, 6, BUF) CVT1(p, 7, BUF)

#define WAITV(N)                                                               \
    asm volatile("s_waitcnt vmcnt(" #N ")" ::: "memory");                      \
    __builtin_amdgcn_sched_barrier(0);

    // prologue: tile0 -> Ab[0]/Bb[0]; A(1) -> Y (in flight)
    LOADA(X, 0);
    stageB(0, 0);
    CVTW(X, 0);          // compiler-inserted vmcnt waits A(0) regs only
    LOADA(Y, 1);

    for (int kt = 0; kt < NKT - 2; kt += 2) {
        // phase kt (even, buf0): Y holds A(kt+1)
        LOADA(X, kt + 2);
        stageB(1, kt + 1);
        WAITV(12);                 // drains A(kt+1)+B(kt); leaves 12 in flight
        compute(0);
        CVTW(Y, 1);
        // phase kt+1 (odd, buf1): X holds A(kt+2)
        if (kt + 3 < NKT) LOADA(Y, kt + 3);
        if (kt + 2 < NKT) stageB(0, kt + 2);
        WAITV(12);
        compute(1);
        CVTW(X, 0);
    }
    // phase 94 (buf0): Y holds A(95); no more A loads
    stageB(1, NKT - 1);
    WAITV(4);                      // drains A(95)+B(94); leaves B(95)
    compute(0);
    CVTW(Y, 1);
    // phase 95 (buf1)
    WAITV(0);
    compute(1);

#undef LOADA
#undef CVT1
#undef CVTW
#undef WAITV

    // epilogue: C row = i*16 + kg*4 + rr ; col = nb*64 + j*16 + lr
    const int seg = nb >> 1;
    const int cb  = (nb & 1) * 64;
    float* obase = out + (size_t)seg * OUT_SEG;
    float bj[4];
    #pragma unroll
    for (int j = 0; j < 4; ++j) bj[j] = bias[nb * 64 + j * 16 + lr];
    #pragma unroll
    for (int i = 0; i < 4; ++i) {
        #pragma unroll
        for (int j = 0; j < 4; ++j) {
            #pragma unroll
            for (int rr = 0; rr < 4; ++rr) {
                int mo = m0 + i * 16 + kg * 4 + rr;
                if (mo < M_TOT)
                    obase[(size_t)mo * G_ + cb + j * 16 + lr] = acc[i][j][rr] + bj[j];
            }
        }
    }
}

// ---------------- KL reduction: stage 1 (per-block partials, no atomics) -----
__global__ __launch_bounds__(256) void kl_kernel(const float* __restrict__ out,
                                                 float* __restrict__ partial)
{
    int wid  = threadIdx.x >> 6;
    int row  = blockIdx.x * 4 + wid;        // M_TOT = 4092*4 exactly
    int lane = threadIdx.x & 63;
    const float* zm  = out;
    const float* zlv = out + OUT_SEG;
    const float* qm  = out + (size_t)2 * OUT_SEG;
    const float* qlv = out + (size_t)3 * OUT_SEG;
    size_t base = (size_t)row * G_;
    float s = 0.f;
    #pragma unroll
    for (int hh = 0; hh < 2; ++hh) {
        int g = lane + hh * 64;
        float a = zm[base + g], b = zlv[base + g];
        float c = qm[base + g], d = qlv[base + g];
        float diff = a - c;
        s += d - b + (__expf(b) + diff * diff) * __expf(-d) - 1.0f;
    }
    #pragma unroll
    for (int off = 32; off > 0; off >>= 1)
        s += __shfl_down(s, off);
    __shared__ float pw[4];
    if (lane == 0) pw[wid] = s;
    __syncthreads();
    if (threadIdx.x == 0)
        partial[blockIdx.x] = pw[0] + pw[1] + pw[2] + pw[3];
}

// ---------------- KL reduction: stage 2 --------------------------------------
__global__ __launch_bounds__(256) void kl_final(const float* __restrict__ partial,
                                                float* __restrict__ out)
{
    float s = 0.f;
    for (int i = threadIdx.x; i < KL_BLOCKS; i += 256) s += partial[i];
    #pragma unroll
    for (int off = 32; off > 0; off >>= 1)
        s += __shfl_down(s, off);
    __shared__ float pw[4];
    int wid = threadIdx.x >> 6;
    int lane = threadIdx.x & 63;
    if (lane == 0) pw[wid] = s;
    __syncthreads();
    if (threadIdx.x == 0)
        out[KL_IDX] = 0.5f * (pw[0] + pw[1] + pw[2] + pw[3]) / (float)M_TOT;
}

// ---------------- launcher ----------------------------------------------------
extern "C" void kernel_launch(void* const* d_in, const int* in_sizes, int n_in,
                              void* d_out, int out_size, void* d_ws, size_t ws_size,
                              hipStream_t stream)
{
    const float* events   = (const float*)d_in[0];
    const float* contexts = (const float*)d_in[1];
    const float* Wzm = (const float*)d_in[2];
    const float* bzm = (const float*)d_in[3];
    const float* Wzv = (const float*)d_in[4];
    const float* bzv = (const float*)d_in[5];
    const float* Wqm = (const float*)d_in[6];
    const float* bqm = (const float*)d_in[7];
    const float* Wqv = (const float*)d_in[8];
    const float* bqv = (const float*)d_in[9];
    float* out = (float*)d_out;

    u16*   wt      = (u16*)((char*)d_ws + WS_WT_OFF);
    float* bias    = (float*)((char*)d_ws + WS_BIAS_OFF);
    float* partial = (float*)((char*)d_ws + WS_PART_OFF);

    prep_kernel<<<512, 256, 0, stream>>>(Wzm, bzm, Wzv, bzv, Wqm, bqm, Wqv, bqv,
                                         wt, bias);
    gemm_kernel<<<2048, 64, 0, stream>>>(events, contexts, wt, bias, out);
    kl_kernel<<<KL_BLOCKS, 256, 0, stream>>>(out, partial);
    kl_final<<<1, 256, 0, stream>>>(partial, out);
}

// Round 9
// 110.430 us; speedup vs baseline: 1.1838x; 1.1838x over previous
//
#include <hip/hip_runtime.h>
#include <stdint.h>

typedef unsigned short u16;
typedef __attribute__((ext_vector_type(8))) short short8;
typedef __attribute__((ext_vector_type(4))) float f32x4;

#define B_      16
#define L_      1024
#define H_      1024
#define G_      128
#define M_TOT   16368            // B*(L-1)
#define K_TOT   3072
#define OUT_SEG 2095104          // M_TOT*G_
#define KL_IDX  (4*OUT_SEG)
#define KL_BLOCKS 4092           // M_TOT / 4 exactly
#define NKT     96               // K_TOT / 32

// ws layout
#define WS_WT_OFF    0           // bf16 W'T [512][3072] = 3,145,728 B
#define WS_BIAS_OFF  3145728     // float[512]
#define WS_PART_OFF  3147776     // float[4092] block partials

__device__ inline u16 f2bf(float f) {
    union { float f; uint32_t u; } x; x.f = f;
    uint32_t u = x.u;
    return (u16)((u + 0x7fffu + ((u >> 16) & 1u)) >> 16);
}

__device__ inline void gload16(const void* g, void* l) {
    __builtin_amdgcn_global_load_lds(
        (const __attribute__((address_space(1))) void*)g,
        (__attribute__((address_space(3))) void*)l, 16, 0, 0);
}

__device__ inline short8 cvt8(f32x4 x, f32x4 y) {
    union { short8 s; uint32_t u[4]; } r;
    asm("v_cvt_pk_bf16_f32 %0, %1, %2" : "=v"(r.u[0]) : "v"(x[0]), "v"(x[1]));
    asm("v_cvt_pk_bf16_f32 %0, %1, %2" : "=v"(r.u[1]) : "v"(x[2]), "v"(x[3]));
    asm("v_cvt_pk_bf16_f32 %0, %1, %2" : "=v"(r.u[2]) : "v"(y[0]), "v"(y[1]));
    asm("v_cvt_pk_bf16_f32 %0, %1, %2" : "=v"(r.u[3]) : "v"(y[2]), "v"(y[3]));
    return r.s;
}

// ---------------- prep: build W'T (bf16, [512][3072]) + bias[512] ------------
__global__ __launch_bounds__(256) void prep_kernel(
    const float* __restrict__ Wzm, const float* __restrict__ bzm,
    const float* __restrict__ Wzv, const float* __restrict__ bzv,
    const float* __restrict__ Wqm, const float* __restrict__ bqm,
    const float* __restrict__ Wqv, const float* __restrict__ bqv,
    u16* __restrict__ wt, float* __restrict__ bias)
{
    int n = blockIdx.x;                 // 0..511 (output column)
    int tid = threadIdx.x;
    const float* W; const float* bsrc; int g; int kmax;
    if (n < 128)      { W = Wzm; bsrc = bzm; g = n;       kmax = 2048; }
    else if (n < 256) { W = Wzv; bsrc = bzv; g = n - 128; kmax = 2048; }
    else if (n < 384) { W = Wqm; bsrc = bqm; g = n - 256; kmax = 3072; }
    else              { W = Wqv; bsrc = bqv; g = n - 384; kmax = 3072; }
    if (tid == 0) bias[n] = bsrc[g];
    #pragma unroll
    for (int i = 0; i < 12; ++i) {
        int k = i * 256 + tid;
        float v = (k < kmax) ? W[(size_t)k * G_ + g] : 0.0f;
        wt[(size_t)n * K_TOT + k] = f2bf(v);
    }
}

// ---------------- GEMM: out[m, 0:512] = ce @ W' + bias ----------------------
// BM=128, BN=128, BK=32, 4 waves (2x2 of 64x64), 512 blocks (2/CU).
// 3-deep LDS ring, ALL staging via global_load_lds (A fp32 + B bf16),
// source-preswizzled. Raw s_barrier + counted vmcnt(12): loads stay in
// flight ~2 tile-phases (>= HBM latency). NO vmcnt(0) drain in main loop.
// A swizzle (8 chunks of 16B per 128B row): chunk ^= (r&7).
// B swizzle (4 slots of 16B per 64B row):  slot  ^= (n>>1)&3.
__global__ __launch_bounds__(256, 2) void gemm_kernel(
    const float* __restrict__ events, const float* __restrict__ contexts,
    const u16* __restrict__ wt, const float* __restrict__ bias,
    float* __restrict__ out)
{
    __shared__ float Af[3][128 * 32];   // fp32 A tiles, swizzled (16 KB each)
    __shared__ u16   Bs[3][128 * 32];   // bf16 B tiles, swizzled (8 KB each)

    const int tid  = threadIdx.x;
    const int bid  = blockIdx.x;
    // XCD swizzle: the 4 nb-blocks sharing an A panel land on one XCD.
    const int xcd  = bid & 7;
    const int nb   = (bid >> 3) & 3;
    const int mp   = xcd * 16 + (bid >> 5);
    const int m0   = mp * 128;

    const int lane = tid & 63;
    const int w    = tid >> 6;
    const int wm   = (w >> 1) * 64;
    const int wn   = (w & 1) * 64;
    const int lr   = lane & 15;
    const int kg   = lane >> 4;          // 0..3

    // ---- A staging sources: 4 chunks/thread, chunk c = it*256+tid ->
    //      row r=c>>3, dest chunk cd=c&7, source chunk cs=cd^(r&7).
    const float* aS0[4]; const float* aS1[4]; const float* aS2[4];
    #pragma unroll
    for (int it = 0; it < 4; ++it) {
        int c  = it * 256 + tid;
        int r  = c >> 3;
        int cs = (c & 7) ^ (r & 7);
        int m = m0 + r; if (m > M_TOT - 1) m = M_TOT - 1;
        int b = m / 1023;
        int t = m - b * 1023;
        aS0[it] = events   + ((size_t)(b * L_ + t)) * H_ + cs * 4;
        aS1[it] = aS0[it] + H_;
        aS2[it] = contexts + ((size_t)(b * (L_ - 1) + t)) * H_ + cs * 4;
    }
    // ---- B staging sources: 2 chunks/thread, c = it*256+tid ->
    //      row nloc=c>>2, dest slot sd=c&3, source slot ss=sd^((nloc>>1)&3).
    const u16* bS[2];
    #pragma unroll
    for (int it = 0; it < 2; ++it) {
        int c    = it * 256 + tid;
        int nloc = c >> 2;
        int ss   = (c & 3) ^ ((nloc >> 1) & 3);
        bS[it] = wt + (size_t)(nb * 128 + nloc) * K_TOT + ss * 8;
    }

    // ---- fragment read offsets ----
    // A: float idx = row*32 + ((cw ^ (row&7))*4), cw = 2*kg, 2*kg+1
    int aoff[4][2];
    // B: u16 idx = nn*32 + ((kg ^ ((nn>>1)&3))<<3)
    int boff[4];
    #pragma unroll
    for (int i = 0; i < 4; ++i) {
        int row = wm + i * 16 + lr;
        aoff[i][0] = row * 32 + (((2 * kg)     ^ (row & 7)) << 2);
        aoff[i][1] = row * 32 + (((2 * kg + 1) ^ (row & 7)) << 2);
        int nn  = wn + i * 16 + lr;
        boff[i] = nn * 32 + ((kg ^ ((nn >> 1) & 3)) << 3);
    }

    f32x4 acc[4][4];
    #pragma unroll
    for (int i = 0; i < 4; ++i)
        #pragma unroll
        for (int j = 0; j < 4; ++j)
            acc[i][j] = (f32x4){0.f, 0.f, 0.f, 0.f};

    auto stage = [&](int buf, int kt) {
        int k0 = kt * 32;
        int rg = k0 >> 10;               // tiles never straddle source regions
        int kq = k0 & 1023;
        #pragma unroll
        for (int it = 0; it < 4; ++it) {
            const float* s = (rg == 0) ? aS0[it] : (rg == 1 ? aS1[it] : aS2[it]);
            gload16(s + kq, &Af[buf][(it * 256 + tid) * 4]);
        }
        #pragma unroll
        for (int it = 0; it < 2; ++it)
            gload16(bS[it] + k0, &Bs[buf][(it * 256 + tid) * 8]);
    };
    auto compute = [&](int buf) {
        short8 a[4], bf[4];
        #pragma unroll
        for (int i = 0; i < 4; ++i) {
            f32x4 x = *(const f32x4*)&Af[buf][aoff[i][0]];
            f32x4 y = *(const f32x4*)&Af[buf][aoff[i][1]];
            a[i] = cvt8(x, y);
        }
        #pragma unroll
        for (int j = 0; j < 4; ++j)
            bf[j] = *(const short8*)&Bs[buf][boff[j]];
        #pragma unroll
        for (int i = 0; i < 4; ++i)
            #pragma unroll
            for (int j = 0; j < 4; ++j)
                acc[i][j] = __builtin_amdgcn_mfma_f32_16x16x32_bf16(
                    a[i], bf[j], acc[i][j], 0, 0, 0);
    };

#define WAITV(N)                                                               \
    asm volatile("s_waitcnt vmcnt(" #N ")" ::: "memory");                      \
    __builtin_amdgcn_sched_barrier(0);
#define LGKM0                                                                  \
    asm volatile("s_waitcnt lgkmcnt(0)" ::: "memory");                         \
    __builtin_amdgcn_sched_barrier(0);
#define BAR __builtin_amdgcn_s_barrier()

    // prologue: two tiles in flight
    stage(0, 0);
    stage(1, 1);

    for (int t = 0; t < 93; t += 3) {
        stage(2, t + 2); WAITV(12); BAR; compute(0); LGKM0; BAR;
        stage(0, t + 3); WAITV(12); BAR; compute(1); LGKM0; BAR;
        stage(1, t + 4); WAITV(12); BAR; compute(2); LGKM0; BAR;
    }
    // t = 93, 94, 95
    stage(2, 95); WAITV(12); BAR; compute(0); LGKM0; BAR;
    WAITV(6);  BAR; compute(1); LGKM0; BAR;
    WAITV(0);  BAR; compute(2);

#undef WAITV
#undef LGKM0
#undef BAR

    // epilogue: C row = wm + i*16 + kg*4 + rr ; col = wn + j*16 + lr
    const float* bptr = bias + nb * 128;
    float* obase = out + (size_t)nb * OUT_SEG;
    #pragma unroll
    for (int i = 0; i < 4; ++i) {
        int mloc = wm + i * 16 + kg * 4;
        #pragma unroll
        for (int j = 0; j < 4; ++j) {
            int g = wn + j * 16 + lr;
            float bv = bptr[g];
            #pragma unroll
            for (int rr = 0; rr < 4; ++rr) {
                int mo = m0 + mloc + rr;
                if (mo < M_TOT) obase[(size_t)mo * G_ + g] = acc[i][j][rr] + bv;
            }
        }
    }
}

// ---------------- KL reduction: stage 1 (per-block partials, no atomics) -----
__global__ __launch_bounds__(256) void kl_kernel(const float* __restrict__ out,
                                                 float* __restrict__ partial)
{
    int wid  = threadIdx.x >> 6;
    int row  = blockIdx.x * 4 + wid;        // M_TOT = 4092*4 exactly
    int lane = threadIdx.x & 63;
    const float* zm  = out;
    const float* zlv = out + OUT_SEG;
    const float* qm  = out + (size_t)2 * OUT_SEG;
    const float* qlv = out + (size_t)3 * OUT_SEG;
    size_t base = (size_t)row * G_;
    float s = 0.f;
    #pragma unroll
    for (int hh = 0; hh < 2; ++hh) {
        int g = lane + hh * 64;
        float a = zm[base + g], b = zlv[base + g];
        float c = qm[base + g], d = qlv[base + g];
        float diff = a - c;
        s += d - b + (__expf(b) + diff * diff) * __expf(-d) - 1.0f;
    }
    #pragma unroll
    for (int off = 32; off > 0; off >>= 1)
        s += __shfl_down(s, off);
    __shared__ float pw[4];
    if (lane == 0) pw[wid] = s;
    __syncthreads();
    if (threadIdx.x == 0)
        partial[blockIdx.x] = pw[0] + pw[1] + pw[2] + pw[3];
}

// ---------------- KL reduction: stage 2 --------------------------------------
__global__ __launch_bounds__(256) void kl_final(const float* __restrict__ partial,
                                                float* __restrict__ out)
{
    float s = 0.f;
    for (int i = threadIdx.x; i < KL_BLOCKS; i += 256) s += partial[i];
    #pragma unroll
    for (int off = 32; off > 0; off >>= 1)
        s += __shfl_down(s, off);
    __shared__ float pw[4];
    int wid = threadIdx.x >> 6;
    int lane = threadIdx.x & 63;
    if (lane == 0) pw[wid] = s;
    __syncthreads();
    if (threadIdx.x == 0)
        out[KL_IDX] = 0.5f * (pw[0] + pw[1] + pw[2] + pw[3]) / (float)M_TOT;
}

// ---------------- launcher ----------------------------------------------------
extern "C" void kernel_launch(void* const* d_in, const int* in_sizes, int n_in,
                              void* d_out, int out_size, void* d_ws, size_t ws_size,
                              hipStream_t stream)
{
    const float* events   = (const float*)d_in[0];
    const float* contexts = (const float*)d_in[1];
    const float* Wzm = (const float*)d_in[2];
    const float* bzm = (const float*)d_in[3];
    const float* Wzv = (const float*)d_in[4];
    const float* bzv = (const float*)d_in[5];
    const float* Wqm = (const float*)d_in[6];
    const float* bqm = (const float*)d_in[7];
    const float* Wqv = (const float*)d_in[8];
    const float* bqv = (const float*)d_in[9];
    float* out = (float*)d_out;

    u16*   wt      = (u16*)((char*)d_ws + WS_WT_OFF);
    float* bias    = (float*)((char*)d_ws + WS_BIAS_OFF);
    float* partial = (float*)((char*)d_ws + WS_PART_OFF);

    prep_kernel<<<512, 256, 0, stream>>>(Wzm, bzm, Wzv, bzv, Wqm, bqm, Wqv, bqv,
                                         wt, bias);
    gemm_kernel<<<512, 256, 0, stream>>>(events, contexts, wt, bias, out);
    kl_kernel<<<KL_BLOCKS, 256, 0, stream>>>(out, partial);
    kl_final<<<1, 256, 0, stream>>>(partial, out);
}